// Round 3
// baseline (171.600 us; speedup 1.0000x reference)
//
#include <hip/hip_runtime.h>

// Problem constants
#define Bn 8
#define Cn 64
#define Hn 128
#define Wn 128
#define On 64
#define K2n 9
#define HWn (Hn * Wn)          // 16384
#define OLP 20                 // offl row stride (floats): 18 + pad

typedef short bf16x8 __attribute__((ext_vector_type(8)));
typedef float f32x4  __attribute__((ext_vector_type(4)));
typedef float f32x2  __attribute__((ext_vector_type(2)));

__device__ __forceinline__ unsigned f2bf(float f) {
    unsigned u = __float_as_uint(f);
    return (u + 0x7FFFu + ((u >> 16) & 1u)) >> 16;   // RNE fp32->bf16
}
__device__ __forceinline__ unsigned pkbf(float lo, float hi) {
    return f2bf(lo) | (f2bf(hi) << 16);              // verified form (R6)
}
__device__ __forceinline__ f32x2 unpk(unsigned u) {  // (lo, hi) bf16 -> f32 pair
    return (f32x2){ __uint_as_float(u << 16), __uint_as_float(u & 0xFFFF0000u) };
}

// ---------------------------------------------------------------------------
// prep: blocks [0,2048): transpose x NCHW fp32 -> xT NHWC bf16-pair.
//       blocks [2048,2200): repack weight + w_off into MFMA B-frag order
//       (wt2[slot][lane][8], slot=(k*2+ks)*4+t, o=t*16+(lane&15),
//        c=ks*32+(lane>>4)*8+j; woffr same with slot=ks*2+t, o>=18 -> 0).
// ---------------------------------------------------------------------------
__global__ __launch_bounds__(256) void prep_kernel(
        const float* __restrict__ x,
        const float* __restrict__ w,
        const float* __restrict__ w_off,
        unsigned* __restrict__ xT,
        unsigned short* __restrict__ wt2,
        unsigned short* __restrict__ woffr) {
    const int tid = threadIdx.x;
    const int bid = blockIdx.x;

    if (bid >= 2048) {                           // ---- weight repack ----
        int i = (bid - 2048) * 256 + tid;        // 38912 = 152*256 exactly
        if (i < K2n * On * Cn) {
            int j    = i & 7;
            int lane = (i >> 3) & 63;
            int slot = i >> 9;
            int t  = slot & 3;
            int ks = (slot >> 2) & 1;
            int k  = slot >> 3;
            int o  = t * 16 + (lane & 15);
            int c  = ks * 32 + (lane >> 4) * 8 + j;
            wt2[i] = (unsigned short)f2bf(w[o * (Cn * K2n) + c * K2n + k]);
        } else {
            int idx  = i - K2n * On * Cn;        // < 2048
            int j    = idx & 7;
            int lane = (idx >> 3) & 63;
            int slot = idx >> 9;                 // 0..3 = ks*2 + t
            int t  = slot & 1;
            int ks = slot >> 1;
            int o  = t * 16 + (lane & 15);
            int c  = ks * 32 + (lane >> 4) * 8 + j;
            woffr[idx] = (o < 18) ? (unsigned short)f2bf(w_off[o * Cn + c]) : 0;
        }
        return;
    }

    // ---- transpose: 64px x 64ch tile ----
    __shared__ float tile[64 * 65];
    const int b   = bid >> 8;
    const int px0 = (bid & 255) << 6;

    {   // float4 reads: thread (c, pq) loads px [pq*16, pq*16+16) of channel c
        const int c = tid >> 2, pq = tid & 3;
        const float4* xp4 = (const float4*)(x + (size_t)b * (Cn * HWn)
                                              + (size_t)c * HWn + px0 + pq * 16);
        float4 v[4];
#pragma unroll
        for (int i = 0; i < 4; i++) v[i] = xp4[i];
#pragma unroll
        for (int i = 0; i < 16; i++)
            tile[(pq * 16 + i) * 65 + c] = (&v[0].x)[i];
    }
    __syncthreads();
    {   // pack + coalesced NHWC write
        const int c2 = tid & 31, r = tid >> 5;
        unsigned* dst = xT + ((size_t)b * HWn + px0) * 32;
#pragma unroll
        for (int j = 0; j < 8; j++) {
            const int p = j * 8 + r;
            dst[p * 32 + c2] = pkbf(tile[p * 65 + c2 * 2], tile[p * 65 + c2 * 2 + 1]);
        }
    }
}

// ---------------------------------------------------------------------------
// Main kernel.  Wave owns 16 px.
// Gather lanes are SP-MAJOR: lane = m*4 + c2 (m = pixel, c2 = 16B chunk), so
// each aligned lane-quad reads contiguous 64B -> TA merges into one request.
// Combined+packed chunks are redistributed to MFMA A-frag lanes via a
// SINGLE-buffered wave-private LDS tile.  Single buffer is safe: reads of
// iteration k are drained (lgkmcnt) before their MFMAs consume them, writes
// of k+1 follow in program order (aliasing LDS ops are never reordered by
// the compiler), and same-wave DS ops execute in order in the LDS pipe.
// R3: LDS 23552 -> 14336 B/block => 8 blocks/CU residency (was 6), VGPR
// held <= 64 via __launch_bounds__(256,8) + reverted (useless) prefetch;
// combine vectorized as f32x2 (v_pk_fma_f32) -> ~40% fewer combine issues.
// ---------------------------------------------------------------------------
struct Tap { float w00, w01, w10, w11; int c00, c01, c10, c11; };

__device__ __forceinline__ Tap mktap(int k, float offy, float offx, int h, int w) {
    Tap s;
    const int kh = k / 3, kw = k - kh * 3;
    const float py  = (float)(h - 1 + kh) + offy;
    const float pxf = (float)(w - 1 + kw) + offx;
    const float y0f = floorf(py), x0f = floorf(pxf);
    const float wy1 = py - y0f, wx1 = pxf - x0f;
    const float wy0 = 1.f - wy1, wx0 = 1.f - wx1;
    const int y0 = (int)y0f, x0i = (int)x0f;
    const int y1 = y0 + 1,  x1 = x0i + 1;
    const bool vy0 = (y0 >= 0) && (y0 < Hn);
    const bool vy1 = (y1 >= 0) && (y1 < Hn);
    const bool vx0 = (x0i >= 0) && (x0i < Wn);
    const bool vx1 = (x1 >= 0) && (x1 < Wn);
    const int yc0 = min(max(y0, 0), Hn - 1), yc1 = min(max(y1, 0), Hn - 1);
    const int xc0 = min(max(x0i, 0), Wn - 1), xc1 = min(max(x1, 0), Wn - 1);
    s.w00 = (vy0 && vx0) ? wy0 * wx0 : 0.f;
    s.w01 = (vy0 && vx1) ? wy0 * wx1 : 0.f;
    s.w10 = (vy1 && vx0) ? wy1 * wx0 : 0.f;
    s.w11 = (vy1 && vx1) ? wy1 * wx1 : 0.f;
    s.c00 = (yc0 * Wn + xc0) * 32; s.c01 = (yc0 * Wn + xc1) * 32;
    s.c10 = (yc1 * Wn + xc0) * 32; s.c11 = (yc1 * Wn + xc1) * 32;
    return s;
}

// bilinear combine of 4 taps; lo/hi bf16 halves share weights -> f32x2 math
// (v_pk_fma_f32: per-component IEEE FMA, halves the FMA issue slots)
__device__ __forceinline__ void combine4(unsigned* dst, const uint4* u, const Tap& s) {
#pragma unroll
    for (int i = 0; i < 4; i++) {
        f32x2 r = unpk((&u[0].x)[i]) * s.w00;
        r += unpk((&u[1].x)[i]) * s.w01;
        r += unpk((&u[2].x)[i]) * s.w10;
        r += unpk((&u[3].x)[i]) * s.w11;
        dst[i] = pkbf(r[0], r[1]);
    }
}

__global__ __launch_bounds__(256, 8) void dcn_kernel(
        const unsigned* __restrict__ xT,
        const unsigned short* __restrict__ wt2,
        const unsigned short* __restrict__ woffr,
        const float* __restrict__ b_off,
        float* __restrict__ out) {
    __shared__ float offl[4 * 16 * OLP];                       // 5120 B
    __shared__ __align__(16) unsigned chunkb[4][16 * 36];      // single-buf chunk tiles, 9216 B

    const int tid = threadIdx.x;
    const int bid = blockIdx.x;
    // XCD swizzle: bid&7 = image -> per-XCD L2 holds one 2.1MB bf16 image
    const int logical = ((bid & 7) << 8) | (bid >> 3);         // 2048 blocks
    const int b   = logical >> 8;
    const int hw0 = (logical & 255) << 6;

    const int lane = tid & 63;
    const int wv   = tid >> 6;
    const int q    = lane >> 4;        // consumer: chunk index / K-half group
    const int sp   = lane & 15;        // consumer + prologue pixel
    const int m    = lane >> 2;        // producer pixel (sp-major gather)
    const int c2   = lane & 3;         // producer 16B-chunk within 64B half
    const int pix0 = hw0 + wv * 16;
    const int pix  = pix0 + sp;

    const unsigned* xb = xT + (size_t)b * (HWn * 32);          // uint = 2 channels

    // ---- offset conv via MFMA (R6-verified) ------------------------------
    {
        union { uint4 u; bf16x8 v; } aw0, aw1;
        aw0.u = *(const uint4*)(xb + pix * 32 + q * 4);
        aw1.u = *(const uint4*)(xb + pix * 32 + 16 + q * 4);
        f32x4 oa0 = (f32x4){0.f, 0.f, 0.f, 0.f};
        f32x4 oa1 = (f32x4){0.f, 0.f, 0.f, 0.f};
        const bf16x8 bo00 = *(const bf16x8*)(woffr + 0 * 512 + lane * 8);
        const bf16x8 bo01 = *(const bf16x8*)(woffr + 1 * 512 + lane * 8);
        const bf16x8 bo10 = *(const bf16x8*)(woffr + 2 * 512 + lane * 8);
        const bf16x8 bo11 = *(const bf16x8*)(woffr + 3 * 512 + lane * 8);
        oa0 = __builtin_amdgcn_mfma_f32_16x16x32_bf16(aw0.v, bo00, oa0, 0, 0, 0);
        oa1 = __builtin_amdgcn_mfma_f32_16x16x32_bf16(aw0.v, bo01, oa1, 0, 0, 0);
        oa0 = __builtin_amdgcn_mfma_f32_16x16x32_bf16(aw1.v, bo10, oa0, 0, 0, 0);
        oa1 = __builtin_amdgcn_mfma_f32_16x16x32_bf16(aw1.v, bo11, oa1, 0, 0, 0);
        const int oc = lane & 15, rg = lane >> 4;
        float* ol = offl + wv * (16 * OLP);
        const float bo_a = b_off[oc];
#pragma unroll
        for (int r = 0; r < 4; r++)
            ol[(rg * 4 + r) * OLP + oc] = oa0[r] + bo_a;
        if (oc < 2) {
            const float bo_b = b_off[16 + oc];
#pragma unroll
            for (int r = 0; r < 4; r++)
                ol[(rg * 4 + r) * OLP + 16 + oc] = oa1[r] + bo_b;
        }
    }
    asm volatile("s_waitcnt lgkmcnt(0)" ::: "memory");   // per-wave LDS hand-off

    // producer-side state: this lane samples pixel m
    const float* olp = offl + wv * (16 * OLP) + m * OLP;
    const int pixm = pix0 + m;
    const int hm = pixm >> 7;
    const int wm = pixm & 127;
    unsigned* cb = &chunkb[wv][0];                       // 576 dwords, single buf

    f32x4 acc[4];
#pragma unroll
    for (int t = 0; t < 4; t++) acc[t] = (f32x4){0.f, 0.f, 0.f, 0.f};

#pragma unroll
    for (int k = 0; k < K2n; k++) {
        // ---- produce: gather (TA-mergeable) + bilinear + pack ----
        const float2 of = *(const float2*)(olp + 2 * k);
        const Tap s = mktap(k, of.x, of.y, hm, wm);

        const unsigned* g00 = xb + s.c00 + c2 * 4;
        const unsigned* g01 = xb + s.c01 + c2 * 4;
        const unsigned* g10 = xb + s.c10 + c2 * 4;
        const unsigned* g11 = xb + s.c11 + c2 * 4;
        uint4 u[8];
        u[0] = *(const uint4*)g00;          // half 0: chunk c2   (ks=0)
        u[1] = *(const uint4*)g01;
        u[2] = *(const uint4*)g10;
        u[3] = *(const uint4*)g11;
        u[4] = *(const uint4*)(g00 + 16);   // half 1: chunk 4+c2 (ks=1)
        u[5] = *(const uint4*)(g01 + 16);
        u[6] = *(const uint4*)(g10 + 16);
        u[7] = *(const uint4*)(g11 + 16);

        unsigned A0[4], A1[4];
        combine4(A0, &u[0], s);             // channels c2*8..+8      (ks=0)
        combine4(A1, &u[4], s);             // channels 32+c2*8..+8   (ks=1)

        // ---- redistribute via single-buffered wave-private LDS ----
        *(uint4*)(cb + m * 36 + c2 * 4)      = make_uint4(A0[0], A0[1], A0[2], A0[3]);
        *(uint4*)(cb + m * 36 + 16 + c2 * 4) = make_uint4(A1[0], A1[1], A1[2], A1[3]);

        // RAW: commit writes before frag reads (full compiler barrier too,
        // which pins the uint4-write/bf16x8-read ordering -> no TBAA hole)
        asm volatile("s_waitcnt lgkmcnt(0)" ::: "memory");

        const bf16x8 af0 = *(const bf16x8*)(cb + sp * 36 + q * 4);
        const bf16x8 af1 = *(const bf16x8*)(cb + sp * 36 + 16 + q * 4);

        const unsigned short* bp = wt2 + (size_t)(k * 8) * 512 + lane * 8;
#pragma unroll
        for (int t = 0; t < 4; t++) {
            const bf16x8 b0 = *(const bf16x8*)(bp + t * 512);
            acc[t] = __builtin_amdgcn_mfma_f32_16x16x32_bf16(af0, b0, acc[t], 0, 0, 0);
            const bf16x8 b1 = *(const bf16x8*)(bp + (4 + t) * 512);
            acc[t] = __builtin_amdgcn_mfma_f32_16x16x32_bf16(af1, b1, acc[t], 0, 0, 0);
        }
    }

    // ---- epilogue: C/D layout col(=o)=lane&15, row(=px)=(lane>>4)*4+r ----
    const int oc = lane & 15;
    const int rg = lane >> 4;
    float* ob = out + (size_t)b * (On * HWn) + pix0 + rg * 4;
#pragma unroll
    for (int t = 0; t < 4; t++) {
        const int o = t * 16 + oc;
        *(f32x4*)(ob + (size_t)o * HWn) = acc[t];
    }
}

// ---------------------------------------------------------------------------
extern "C" void kernel_launch(void* const* d_in, const int* in_sizes, int n_in,
                              void* d_out, int out_size, void* d_ws, size_t ws_size,
                              hipStream_t stream) {
    const float* x      = (const float*)d_in[0];   // (8,64,128,128)
    const float* weight = (const float*)d_in[1];   // (64,64,3,3)
    const float* w_off  = (const float*)d_in[2];   // (18,64)
    const float* b_off  = (const float*)d_in[3];   // (18,)
    float* out = (float*)d_out;                    // (8,64,128,128)

    // workspace: xT 16 MB | wt2 73728 B | woffr 4096 B
    unsigned*       xT    = (unsigned*)d_ws;
    unsigned short* wt2   = (unsigned short*)((char*)d_ws + 16777216);
    unsigned short* woffr = (unsigned short*)((char*)d_ws + 16777216 + 73728);

    prep_kernel<<<2200, 256, 0, stream>>>(x, weight, w_off, xT, wt2, woffr);
    dcn_kernel<<<2048, 256, 0, stream>>>(xT, wt2, woffr, b_off, out);
}

// Round 7
// 133.511 us; speedup vs baseline: 1.2853x; 1.2853x over previous
//
#include <hip/hip_runtime.h>

// Problem constants
#define Bn 8
#define Cn 64
#define Hn 128
#define Wn 128
#define On 64
#define K2n 9
#define HWn (Hn * Wn)          // 16384
#define OLP 20                 // offl row stride (floats): 18 + pad

typedef short bf16x8 __attribute__((ext_vector_type(8)));
typedef float f32x4  __attribute__((ext_vector_type(4)));

__device__ __forceinline__ unsigned f2bf(float f) {
    unsigned u = __float_as_uint(f);
    return (u + 0x7FFFu + ((u >> 16) & 1u)) >> 16;   // RNE fp32->bf16
}
__device__ __forceinline__ unsigned pkbf(float lo, float hi) {
    return f2bf(lo) | (f2bf(hi) << 16);              // verified form (R6)
}
__device__ __forceinline__ float bflo(unsigned u) { return __uint_as_float(u << 16); }
__device__ __forceinline__ float bfhi(unsigned u) { return __uint_as_float(u & 0xFFFF0000u); }

// ---------------------------------------------------------------------------
// prep: blocks [0,2048): transpose x NCHW fp32 -> xT NHWC bf16-pair.
//       blocks [2048,2200): repack weight + w_off into MFMA B-frag order
//       (wt2[slot][lane][8], slot=(k*2+ks)*4+t, o=t*16+(lane&15),
//        c=ks*32+(lane>>4)*8+j; woffr same with slot=ks*2+t, o>=18 -> 0).
// ---------------------------------------------------------------------------
__global__ __launch_bounds__(256) void prep_kernel(
        const float* __restrict__ x,
        const float* __restrict__ w,
        const float* __restrict__ w_off,
        unsigned* __restrict__ xT,
        unsigned short* __restrict__ wt2,
        unsigned short* __restrict__ woffr) {
    const int tid = threadIdx.x;
    const int bid = blockIdx.x;

    if (bid >= 2048) {                           // ---- weight repack ----
        int i = (bid - 2048) * 256 + tid;        // 38912 = 152*256 exactly
        if (i < K2n * On * Cn) {
            int j    = i & 7;
            int lane = (i >> 3) & 63;
            int slot = i >> 9;
            int t  = slot & 3;
            int ks = (slot >> 2) & 1;
            int k  = slot >> 3;
            int o  = t * 16 + (lane & 15);
            int c  = ks * 32 + (lane >> 4) * 8 + j;
            wt2[i] = (unsigned short)f2bf(w[o * (Cn * K2n) + c * K2n + k]);
        } else {
            int idx  = i - K2n * On * Cn;        // < 2048
            int j    = idx & 7;
            int lane = (idx >> 3) & 63;
            int slot = idx >> 9;                 // 0..3 = ks*2 + t
            int t  = slot & 1;
            int ks = slot >> 1;
            int o  = t * 16 + (lane & 15);
            int c  = ks * 32 + (lane >> 4) * 8 + j;
            woffr[idx] = (o < 18) ? (unsigned short)f2bf(w_off[o * Cn + c]) : 0;
        }
        return;
    }

    // ---- transpose: 64px x 64ch tile ----
    __shared__ float tile[64 * 65];
    const int b   = bid >> 8;
    const int px0 = (bid & 255) << 6;

    {   // float4 reads: thread (c, pq) loads px [pq*16, pq*16+16) of channel c
        const int c = tid >> 2, pq = tid & 3;
        const float4* xp4 = (const float4*)(x + (size_t)b * (Cn * HWn)
                                              + (size_t)c * HWn + px0 + pq * 16);
        float4 v[4];
#pragma unroll
        for (int i = 0; i < 4; i++) v[i] = xp4[i];
#pragma unroll
        for (int i = 0; i < 16; i++)
            tile[(pq * 16 + i) * 65 + c] = (&v[0].x)[i];
    }
    __syncthreads();
    {   // pack + coalesced NHWC write
        const int c2 = tid & 31, r = tid >> 5;
        unsigned* dst = xT + ((size_t)b * HWn + px0) * 32;
#pragma unroll
        for (int j = 0; j < 8; j++) {
            const int p = j * 8 + r;
            dst[p * 32 + c2] = pkbf(tile[p * 65 + c2 * 2], tile[p * 65 + c2 * 2 + 1]);
        }
    }
}

// ---------------------------------------------------------------------------
// Main kernel.  Wave owns 16 px.
// Gather lanes are SP-MAJOR: lane = m*4 + c2 (m = pixel, c2 = 16B chunk), so
// each aligned lane-quad reads contiguous 64B -> TA merges into one request.
// Combined+packed chunks are redistributed to MFMA A-frag lanes via the
// R0-VERBATIM double-buffered wave-private LDS tile (alternating (k&1)
// buffers, one lgkm clobber per k) with R0's SCALAR combine4.
//
// R7 session ledger:
//  - f32x2 packed combine: present in ALL 4 corrupt rounds (R1/R4/R5/R6),
//    only "passed" inside R3's degenerate spill-serialized codegen =>
//    ABANDONED (suspected packed-op miscompile under healthy scheduling).
//  - single-/sub-buffer chunk reuse: abandoned with it (confounded).
//  - THIS round's single new mechanism: offsets hoisted to registers
//    (R2-verified) making offl dead during the k-loop, so offl ALIASES the
//    chunk-tile storage (union).  The overlap is cross-wave, so one
//    __syncthreads() separates all offl reads from the first chunk write --
//    a compiler-level AND hw-level full barrier (s_waitcnt+s_barrier), not
//    a hand-rolled fence.  LDS: 23552 -> 18432 B => 8 blocks/CU (grid = 8).
// ---------------------------------------------------------------------------
struct Tap { float w00, w01, w10, w11; int c00, c01, c10, c11; };

__device__ __forceinline__ Tap mktap(int k, float offy, float offx, int h, int w) {
    Tap s;
    const int kh = k / 3, kw = k - kh * 3;
    const float py  = (float)(h - 1 + kh) + offy;
    const float pxf = (float)(w - 1 + kw) + offx;
    const float y0f = floorf(py), x0f = floorf(pxf);
    const float wy1 = py - y0f, wx1 = pxf - x0f;
    const float wy0 = 1.f - wy1, wx0 = 1.f - wx1;
    const int y0 = (int)y0f, x0i = (int)x0f;
    const int y1 = y0 + 1,  x1 = x0i + 1;
    const bool vy0 = (y0 >= 0) && (y0 < Hn);
    const bool vy1 = (y1 >= 0) && (y1 < Hn);
    const bool vx0 = (x0i >= 0) && (x0i < Wn);
    const bool vx1 = (x1 >= 0) && (x1 < Wn);
    const int yc0 = min(max(y0, 0), Hn - 1), yc1 = min(max(y1, 0), Hn - 1);
    const int xc0 = min(max(x0i, 0), Wn - 1), xc1 = min(max(x1, 0), Wn - 1);
    s.w00 = (vy0 && vx0) ? wy0 * wx0 : 0.f;
    s.w01 = (vy0 && vx1) ? wy0 * wx1 : 0.f;
    s.w10 = (vy1 && vx0) ? wy1 * wx0 : 0.f;
    s.w11 = (vy1 && vx1) ? wy1 * wx1 : 0.f;
    s.c00 = (yc0 * Wn + xc0) * 32; s.c01 = (yc0 * Wn + xc1) * 32;
    s.c10 = (yc1 * Wn + xc0) * 32; s.c11 = (yc1 * Wn + xc1) * 32;
    return s;
}

// scalar bilinear combine (R0-verbatim; the f32x2 packed variant is
// abandoned -- see ledger above)
__device__ __forceinline__ void combine4(unsigned* dst, const uint4* u, const Tap& s) {
#pragma unroll
    for (int i = 0; i < 4; i++) {
        const unsigned a = (&u[0].x)[i], b = (&u[1].x)[i];
        const unsigned c = (&u[2].x)[i], d = (&u[3].x)[i];
        const float slo = s.w00 * bflo(a) + s.w01 * bflo(b)
                        + s.w10 * bflo(c) + s.w11 * bflo(d);
        const float shi = s.w00 * bfhi(a) + s.w01 * bfhi(b)
                        + s.w10 * bfhi(c) + s.w11 * bfhi(d);
        dst[i] = pkbf(slo, shi);
    }
}

__global__ __launch_bounds__(256, 4) void dcn_kernel(
        const unsigned* __restrict__ xT,
        const unsigned short* __restrict__ wt2,
        const unsigned short* __restrict__ woffr,
        const float* __restrict__ b_off,
        float* __restrict__ out) {
    // Single LDS block: chunk tiles for the k-loop; its first 5120 B double
    // as the offset staging area (offl) during the prologue only.
    __shared__ __align__(16) unsigned shmem[4][2][16 * 36];    // 18432 B
    float* const offl = (float*)&shmem[0][0][0];               // prologue alias

    const int tid = threadIdx.x;
    const int bid = blockIdx.x;
    // XCD swizzle: bid&7 = image -> per-XCD L2 holds one 2.1MB bf16 image
    const int logical = ((bid & 7) << 8) | (bid >> 3);         // 2048 blocks
    const int b   = logical >> 8;
    const int hw0 = (logical & 255) << 6;

    const int lane = tid & 63;
    const int wv   = tid >> 6;
    const int q    = lane >> 4;        // consumer: chunk index / K-half group
    const int sp   = lane & 15;        // consumer + prologue pixel
    const int m    = lane >> 2;        // producer pixel (sp-major gather)
    const int c2   = lane & 3;         // producer 16B-chunk within 64B half
    const int pix0 = hw0 + wv * 16;
    const int pix  = pix0 + sp;

    const unsigned* xb = xT + (size_t)b * (HWn * 32);          // uint = 2 channels

    // ---- offset conv via MFMA (R6-verified) ------------------------------
    {
        union { uint4 u; bf16x8 v; } aw0, aw1;
        aw0.u = *(const uint4*)(xb + pix * 32 + q * 4);
        aw1.u = *(const uint4*)(xb + pix * 32 + 16 + q * 4);
        f32x4 oa0 = (f32x4){0.f, 0.f, 0.f, 0.f};
        f32x4 oa1 = (f32x4){0.f, 0.f, 0.f, 0.f};
        const bf16x8 bo00 = *(const bf16x8*)(woffr + 0 * 512 + lane * 8);
        const bf16x8 bo01 = *(const bf16x8*)(woffr + 1 * 512 + lane * 8);
        const bf16x8 bo10 = *(const bf16x8*)(woffr + 2 * 512 + lane * 8);
        const bf16x8 bo11 = *(const bf16x8*)(woffr + 3 * 512 + lane * 8);
        oa0 = __builtin_amdgcn_mfma_f32_16x16x32_bf16(aw0.v, bo00, oa0, 0, 0, 0);
        oa1 = __builtin_amdgcn_mfma_f32_16x16x32_bf16(aw0.v, bo01, oa1, 0, 0, 0);
        oa0 = __builtin_amdgcn_mfma_f32_16x16x32_bf16(aw1.v, bo10, oa0, 0, 0, 0);
        oa1 = __builtin_amdgcn_mfma_f32_16x16x32_bf16(aw1.v, bo11, oa1, 0, 0, 0);
        const int oc = lane & 15, rg = lane >> 4;
        float* ol = offl + wv * (16 * OLP);
        const float bo_a = b_off[oc];
#pragma unroll
        for (int r = 0; r < 4; r++)
            ol[(rg * 4 + r) * OLP + oc] = oa0[r] + bo_a;
        if (oc < 2) {
            const float bo_b = b_off[16 + oc];
#pragma unroll
            for (int r = 0; r < 4; r++)
                ol[(rg * 4 + r) * OLP + 16 + oc] = oa1[r] + bo_b;
        }
    }
    asm volatile("s_waitcnt lgkmcnt(0)" ::: "memory");   // per-wave LDS hand-off

    // hoist this lane's 18 offsets (pixel m) into registers (R2-verified),
    // making the offl region dead before any chunk write
    const float* olp = offl + wv * (16 * OLP) + m * OLP;
    float off[18];
#pragma unroll
    for (int i = 0; i < 9; i++) {
        const float2 o2 = *(const float2*)(olp + 2 * i);
        off[2 * i]     = o2.x;
        off[2 * i + 1] = o2.y;
    }

    // cross-wave overlap barrier: ALL offl reads complete before ANY wave's
    // chunk writes touch the shared storage (full compiler + hw barrier)
    __syncthreads();

    // producer-side state: this lane samples pixel m
    const int pixm = pix0 + m;
    const int hm = pixm >> 7;
    const int wm = pixm & 127;
    unsigned* cwv = &shmem[wv][0][0];                    // 2 x 576 dwords

    f32x4 acc[4];
#pragma unroll
    for (int t = 0; t < 4; t++) acc[t] = (f32x4){0.f, 0.f, 0.f, 0.f};

#pragma unroll
    for (int k = 0; k < K2n; k++) {
        // ---- produce: gather (TA-mergeable) + bilinear + pack ----
        const Tap s = mktap(k, off[2 * k], off[2 * k + 1], hm, wm);

        const unsigned* g00 = xb + s.c00 + c2 * 4;
        const unsigned* g01 = xb + s.c01 + c2 * 4;
        const unsigned* g10 = xb + s.c10 + c2 * 4;
        const unsigned* g11 = xb + s.c11 + c2 * 4;
        uint4 u[8];
        u[0] = *(const uint4*)g00;          // half 0: chunk c2   (ks=0)
        u[1] = *(const uint4*)g01;
        u[2] = *(const uint4*)g10;
        u[3] = *(const uint4*)g11;
        u[4] = *(const uint4*)(g00 + 16);   // half 1: chunk 4+c2 (ks=1)
        u[5] = *(const uint4*)(g01 + 16);
        u[6] = *(const uint4*)(g10 + 16);
        u[7] = *(const uint4*)(g11 + 16);

        unsigned A0[4], A1[4];
        combine4(A0, &u[0], s);             // channels c2*8..+8      (ks=0)
        combine4(A1, &u[4], s);             // channels 32+c2*8..+8   (ks=1)

        // ---- redistribute via double-buffered wave-private LDS ----
        unsigned* cb = cwv + (k & 1) * 576;
        *(uint4*)(cb + m * 36 + c2 * 4)      = make_uint4(A0[0], A0[1], A0[2], A0[3]);
        *(uint4*)(cb + m * 36 + 16 + c2 * 4) = make_uint4(A1[0], A1[1], A1[2], A1[3]);

        // RAW: commit writes before frag reads (full compiler barrier too,
        // which pins the uint4-write/bf16x8-read ordering -> no TBAA hole)
        asm volatile("s_waitcnt lgkmcnt(0)" ::: "memory");

        const bf16x8 af0 = *(const bf16x8*)(cb + sp * 36 + q * 4);
        const bf16x8 af1 = *(const bf16x8*)(cb + sp * 36 + 16 + q * 4);

        const unsigned short* bp = wt2 + (size_t)(k * 8) * 512 + lane * 8;
#pragma unroll
        for (int t = 0; t < 4; t++) {
            const bf16x8 b0 = *(const bf16x8*)(bp + t * 512);
            acc[t] = __builtin_amdgcn_mfma_f32_16x16x32_bf16(af0, b0, acc[t], 0, 0, 0);
            const bf16x8 b1 = *(const bf16x8*)(bp + (4 + t) * 512);
            acc[t] = __builtin_amdgcn_mfma_f32_16x16x32_bf16(af1, b1, acc[t], 0, 0, 0);
        }
    }

    // ---- epilogue: C/D layout col(=o)=lane&15, row(=px)=(lane>>4)*4+r ----
    const int oc = lane & 15;
    const int rg = lane >> 4;
    float* ob = out + (size_t)b * (On * HWn) + pix0 + rg * 4;
#pragma unroll
    for (int t = 0; t < 4; t++) {
        const int o = t * 16 + oc;
        *(f32x4*)(ob + (size_t)o * HWn) = acc[t];
    }
}

// ---------------------------------------------------------------------------
extern "C" void kernel_launch(void* const* d_in, const int* in_sizes, int n_in,
                              void* d_out, int out_size, void* d_ws, size_t ws_size,
                              hipStream_t stream) {
    const float* x      = (const float*)d_in[0];   // (8,64,128,128)
    const float* weight = (const float*)d_in[1];   // (64,64,3,3)
    const float* w_off  = (const float*)d_in[2];   // (18,64)
    const float* b_off  = (const float*)d_in[3];   // (18,)
    float* out = (float*)d_out;                    // (8,64,128,128)

    // workspace: xT 16 MB | wt2 73728 B | woffr 4096 B
    unsigned*       xT    = (unsigned*)d_ws;
    unsigned short* wt2   = (unsigned short*)((char*)d_ws + 16777216);
    unsigned short* woffr = (unsigned short*)((char*)d_ws + 16777216 + 73728);

    prep_kernel<<<2200, 256, 0, stream>>>(x, weight, w_off, xT, wt2, woffr);
    dcn_kernel<<<2048, 256, 0, stream>>>(xT, wt2, woffr, b_off, out);
}

// Round 8
// 131.595 us; speedup vs baseline: 1.3040x; 1.0146x over previous
//
#include <hip/hip_runtime.h>

// Problem constants
#define Bn 8
#define Cn 64
#define Hn 128
#define Wn 128
#define On 64
#define K2n 9
#define HWn (Hn * Wn)          // 16384
#define OLP 20                 // offl row stride (floats): 18 + pad

typedef short bf16x8 __attribute__((ext_vector_type(8)));
typedef float f32x4  __attribute__((ext_vector_type(4)));

__device__ __forceinline__ unsigned f2bf(float f) {
    unsigned u = __float_as_uint(f);
    return (u + 0x7FFFu + ((u >> 16) & 1u)) >> 16;   // RNE fp32->bf16
}
__device__ __forceinline__ unsigned pkbf(float lo, float hi) {
    return f2bf(lo) | (f2bf(hi) << 16);              // verified form (R6)
}
__device__ __forceinline__ float bflo(unsigned u) { return __uint_as_float(u << 16); }
__device__ __forceinline__ float bfhi(unsigned u) { return __uint_as_float(u & 0xFFFF0000u); }

// ---------------------------------------------------------------------------
// prep: blocks [0,2048): transpose x NCHW fp32 -> xT NHWC bf16-pair.
//       blocks [2048,2200): repack weight + w_off into MFMA B-frag order
//       (wt2[slot][lane][8], slot=(k*2+ks)*4+t, o=t*16+(lane&15),
//        c=ks*32+(lane>>4)*8+j; woffr same with slot=ks*2+t, o>=18 -> 0).
// ---------------------------------------------------------------------------
__global__ __launch_bounds__(256) void prep_kernel(
        const float* __restrict__ x,
        const float* __restrict__ w,
        const float* __restrict__ w_off,
        unsigned* __restrict__ xT,
        unsigned short* __restrict__ wt2,
        unsigned short* __restrict__ woffr) {
    const int tid = threadIdx.x;
    const int bid = blockIdx.x;

    if (bid >= 2048) {                           // ---- weight repack ----
        int i = (bid - 2048) * 256 + tid;        // 38912 = 152*256 exactly
        if (i < K2n * On * Cn) {
            int j    = i & 7;
            int lane = (i >> 3) & 63;
            int slot = i >> 9;
            int t  = slot & 3;
            int ks = (slot >> 2) & 1;
            int k  = slot >> 3;
            int o  = t * 16 + (lane & 15);
            int c  = ks * 32 + (lane >> 4) * 8 + j;
            wt2[i] = (unsigned short)f2bf(w[o * (Cn * K2n) + c * K2n + k]);
        } else {
            int idx  = i - K2n * On * Cn;        // < 2048
            int j    = idx & 7;
            int lane = (idx >> 3) & 63;
            int slot = idx >> 9;                 // 0..3 = ks*2 + t
            int t  = slot & 1;
            int ks = slot >> 1;
            int o  = t * 16 + (lane & 15);
            int c  = ks * 32 + (lane >> 4) * 8 + j;
            woffr[idx] = (o < 18) ? (unsigned short)f2bf(w_off[o * Cn + c]) : 0;
        }
        return;
    }

    // ---- transpose: 64px x 64ch tile ----
    __shared__ float tile[64 * 65];
    const int b   = bid >> 8;
    const int px0 = (bid & 255) << 6;

    {   // float4 reads: thread (c, pq) loads px [pq*16, pq*16+16) of channel c
        const int c = tid >> 2, pq = tid & 3;
        const float4* xp4 = (const float4*)(x + (size_t)b * (Cn * HWn)
                                              + (size_t)c * HWn + px0 + pq * 16);
        float4 v[4];
#pragma unroll
        for (int i = 0; i < 4; i++) v[i] = xp4[i];
#pragma unroll
        for (int i = 0; i < 16; i++)
            tile[(pq * 16 + i) * 65 + c] = (&v[0].x)[i];
    }
    __syncthreads();
    {   // pack + coalesced NHWC write
        const int c2 = tid & 31, r = tid >> 5;
        unsigned* dst = xT + ((size_t)b * HWn + px0) * 32;
#pragma unroll
        for (int j = 0; j < 8; j++) {
            const int p = j * 8 + r;
            dst[p * 32 + c2] = pkbf(tile[p * 65 + c2 * 2], tile[p * 65 + c2 * 2 + 1]);
        }
    }
}

// ---------------------------------------------------------------------------
// Main kernel.  Wave owns 16 px.
// Gather lanes are SP-MAJOR: lane = m*4 + c2 (m = pixel, c2 = 16B chunk), so
// each aligned lane-quad reads contiguous 64B -> TA merges into one request.
// Redistribution: R0-VERBATIM double-buffered wave-private LDS tile
// (alternating (k&1) buffers, one lgkm clobber per k), SCALAR combine4.
//
// R8 theory (from R7's flat counters): waves stall ~54% of resident time on
// in-loop memory latency.  Two causes: (a) the per-k asm "memory" clobber
// pins ALL loads -- including the 8 wt2 B-frag loads that sit after the
// drain, right before the MFMAs (~200cy L2 hit each k, never prefetched);
// (b) at VGPR=64 ((256,4) + allocator) there is no room to hold prefetched
// state, so R2's gather prefetch was silently sunk back to its use site.
// Fix: issue k+1's gather AND wt2 loads in source BEFORE the clobber (they
// then cannot sink below it) and raise the VGPR cap via (256,2) so the
// ping-pong state (u 32 + wt 32 + off 18 + acc 16 + addr ~25 ~= 125 VGPR)
// stays register-resident.  At ~128 VGPR the HW still allows 4 waves/SIMD
// >= the measured residency of ~2.7, so no occupancy loss.
// Session ledger (unchanged): f32x2 packed combine + single-buffer reuse
// ABANDONED (4 corrupt rounds); offl-aliased-into-chunkb + off[18] hoist
// verified in R7; u-ping-pong data path verified in R2.
// ---------------------------------------------------------------------------
struct Tap { float w00, w01, w10, w11; int c00, c01, c10, c11; };

__device__ __forceinline__ Tap mktap(int k, float offy, float offx, int h, int w) {
    Tap s;
    const int kh = k / 3, kw = k - kh * 3;
    const float py  = (float)(h - 1 + kh) + offy;
    const float pxf = (float)(w - 1 + kw) + offx;
    const float y0f = floorf(py), x0f = floorf(pxf);
    const float wy1 = py - y0f, wx1 = pxf - x0f;
    const float wy0 = 1.f - wy1, wx0 = 1.f - wx1;
    const int y0 = (int)y0f, x0i = (int)x0f;
    const int y1 = y0 + 1,  x1 = x0i + 1;
    const bool vy0 = (y0 >= 0) && (y0 < Hn);
    const bool vy1 = (y1 >= 0) && (y1 < Hn);
    const bool vx0 = (x0i >= 0) && (x0i < Wn);
    const bool vx1 = (x1 >= 0) && (x1 < Wn);
    const int yc0 = min(max(y0, 0), Hn - 1), yc1 = min(max(y1, 0), Hn - 1);
    const int xc0 = min(max(x0i, 0), Wn - 1), xc1 = min(max(x1, 0), Wn - 1);
    s.w00 = (vy0 && vx0) ? wy0 * wx0 : 0.f;
    s.w01 = (vy0 && vx1) ? wy0 * wx1 : 0.f;
    s.w10 = (vy1 && vx0) ? wy1 * wx0 : 0.f;
    s.w11 = (vy1 && vx1) ? wy1 * wx1 : 0.f;
    s.c00 = (yc0 * Wn + xc0) * 32; s.c01 = (yc0 * Wn + xc1) * 32;
    s.c10 = (yc1 * Wn + xc0) * 32; s.c11 = (yc1 * Wn + xc1) * 32;
    return s;
}

// scalar bilinear combine (R0-verbatim; packed f32x2 variant abandoned)
__device__ __forceinline__ void combine4(unsigned* dst, const uint4* u, const Tap& s) {
#pragma unroll
    for (int i = 0; i < 4; i++) {
        const unsigned a = (&u[0].x)[i], b = (&u[1].x)[i];
        const unsigned c = (&u[2].x)[i], d = (&u[3].x)[i];
        const float slo = s.w00 * bflo(a) + s.w01 * bflo(b)
                        + s.w10 * bflo(c) + s.w11 * bflo(d);
        const float shi = s.w00 * bfhi(a) + s.w01 * bfhi(b)
                        + s.w10 * bfhi(c) + s.w11 * bfhi(d);
        dst[i] = pkbf(slo, shi);
    }
}

__device__ __forceinline__ void gather8(uint4* u, const unsigned* xb,
                                        const Tap& s, int c2) {
    const unsigned* g00 = xb + s.c00 + c2 * 4;
    const unsigned* g01 = xb + s.c01 + c2 * 4;
    const unsigned* g10 = xb + s.c10 + c2 * 4;
    const unsigned* g11 = xb + s.c11 + c2 * 4;
    u[0] = *(const uint4*)g00;          // half 0: chunk c2   (ks=0)
    u[1] = *(const uint4*)g01;
    u[2] = *(const uint4*)g10;
    u[3] = *(const uint4*)g11;
    u[4] = *(const uint4*)(g00 + 16);   // half 1: chunk 4+c2 (ks=1)
    u[5] = *(const uint4*)(g01 + 16);
    u[6] = *(const uint4*)(g10 + 16);
    u[7] = *(const uint4*)(g11 + 16);
}

__global__ __launch_bounds__(256, 2) void dcn_kernel(
        const unsigned* __restrict__ xT,
        const unsigned short* __restrict__ wt2,
        const unsigned short* __restrict__ woffr,
        const float* __restrict__ b_off,
        float* __restrict__ out) {
    // Single LDS block: chunk tiles for the k-loop; its first 5120 B double
    // as the offset staging area (offl) during the prologue only (R7-verified).
    __shared__ __align__(16) unsigned shmem[4][2][16 * 36];    // 18432 B
    float* const offl = (float*)&shmem[0][0][0];               // prologue alias

    const int tid = threadIdx.x;
    const int bid = blockIdx.x;
    // XCD swizzle: bid&7 = image -> per-XCD L2 holds one 2.1MB bf16 image
    const int logical = ((bid & 7) << 8) | (bid >> 3);         // 2048 blocks
    const int b   = logical >> 8;
    const int hw0 = (logical & 255) << 6;

    const int lane = tid & 63;
    const int wv   = tid >> 6;
    const int q    = lane >> 4;        // consumer: chunk index / K-half group
    const int sp   = lane & 15;        // consumer + prologue pixel
    const int m    = lane >> 2;        // producer pixel (sp-major gather)
    const int c2   = lane & 3;         // producer 16B-chunk within 64B half
    const int pix0 = hw0 + wv * 16;
    const int pix  = pix0 + sp;

    const unsigned* xb = xT + (size_t)b * (HWn * 32);          // uint = 2 channels

    // ---- offset conv via MFMA (R6-verified) ------------------------------
    {
        union { uint4 u; bf16x8 v; } aw0, aw1;
        aw0.u = *(const uint4*)(xb + pix * 32 + q * 4);
        aw1.u = *(const uint4*)(xb + pix * 32 + 16 + q * 4);
        f32x4 oa0 = (f32x4){0.f, 0.f, 0.f, 0.f};
        f32x4 oa1 = (f32x4){0.f, 0.f, 0.f, 0.f};
        const bf16x8 bo00 = *(const bf16x8*)(woffr + 0 * 512 + lane * 8);
        const bf16x8 bo01 = *(const bf16x8*)(woffr + 1 * 512 + lane * 8);
        const bf16x8 bo10 = *(const bf16x8*)(woffr + 2 * 512 + lane * 8);
        const bf16x8 bo11 = *(const bf16x8*)(woffr + 3 * 512 + lane * 8);
        oa0 = __builtin_amdgcn_mfma_f32_16x16x32_bf16(aw0.v, bo00, oa0, 0, 0, 0);
        oa1 = __builtin_amdgcn_mfma_f32_16x16x32_bf16(aw0.v, bo01, oa1, 0, 0, 0);
        oa0 = __builtin_amdgcn_mfma_f32_16x16x32_bf16(aw1.v, bo10, oa0, 0, 0, 0);
        oa1 = __builtin_amdgcn_mfma_f32_16x16x32_bf16(aw1.v, bo11, oa1, 0, 0, 0);
        const int oc = lane & 15, rg = lane >> 4;
        float* ol = offl + wv * (16 * OLP);
        const float bo_a = b_off[oc];
#pragma unroll
        for (int r = 0; r < 4; r++)
            ol[(rg * 4 + r) * OLP + oc] = oa0[r] + bo_a;
        if (oc < 2) {
            const float bo_b = b_off[16 + oc];
#pragma unroll
            for (int r = 0; r < 4; r++)
                ol[(rg * 4 + r) * OLP + 16 + oc] = oa1[r] + bo_b;
        }
    }
    asm volatile("s_waitcnt lgkmcnt(0)" ::: "memory");   // per-wave LDS hand-off

    // hoist this lane's 18 offsets (pixel m) into registers (R2/R7-verified),
    // making the offl region dead before any chunk write
    const float* olp = offl + wv * (16 * OLP) + m * OLP;
    float off[18];
#pragma unroll
    for (int i = 0; i < 9; i++) {
        const float2 o2 = *(const float2*)(olp + 2 * i);
        off[2 * i]     = o2.x;
        off[2 * i + 1] = o2.y;
    }

    // cross-wave overlap barrier: ALL offl reads complete before ANY wave's
    // chunk writes touch the shared storage (full compiler + hw barrier)
    __syncthreads();

    // producer-side state: this lane samples pixel m
    const int pixm = pix0 + m;
    const int hm = pixm >> 7;
    const int wm = pixm & 127;
    unsigned* cwv = &shmem[wv][0][0];                    // 2 x 576 dwords

    f32x4 acc[4];
#pragma unroll
    for (int t = 0; t < 4; t++) acc[t] = (f32x4){0.f, 0.f, 0.f, 0.f};

    // ---- software pipeline state: gather + B-frag regs for k=0 ----------
    uint4  u[2][8];                    // ping-pong gather state
    bf16x8 wtr[2][8];                  // ping-pong B-fragments
    Tap    tp[2];
    tp[0] = mktap(0, off[0], off[1], hm, wm);
    gather8(u[0], xb, tp[0], c2);
    {
        const unsigned short* bp0 = wt2 + (size_t)0 * 512 + lane * 8;
#pragma unroll
        for (int t = 0; t < 8; t++) wtr[0][t] = *(const bf16x8*)(bp0 + t * 512);
    }

#pragma unroll
    for (int k = 0; k < K2n; k++) {
        const int cur = k & 1, nxt = cur ^ 1;

        // ---- issue k+1's loads FIRST, in source BEFORE this iteration's
        //      clobber: they cannot sink below it, so their latency hides
        //      under combine(k) + drain + MFMA(k) ----
        if (k + 1 < K2n) {
            tp[nxt] = mktap(k + 1, off[2 * k + 2], off[2 * k + 3], hm, wm);
            gather8(u[nxt], xb, tp[nxt], c2);
            const unsigned short* bpn = wt2 + (size_t)((k + 1) * 8) * 512 + lane * 8;
#pragma unroll
            for (int t = 0; t < 8; t++) wtr[nxt][t] = *(const bf16x8*)(bpn + t * 512);
        }

        // ---- combine current k's taps + pack ----
        unsigned A0[4], A1[4];
        combine4(A0, &u[cur][0], tp[cur]);  // channels c2*8..+8      (ks=0)
        combine4(A1, &u[cur][4], tp[cur]);  // channels 32+c2*8..+8   (ks=1)

        // ---- redistribute via double-buffered wave-private LDS ----
        unsigned* cb = cwv + cur * 576;
        *(uint4*)(cb + m * 36 + c2 * 4)      = make_uint4(A0[0], A0[1], A0[2], A0[3]);
        *(uint4*)(cb + m * 36 + 16 + c2 * 4) = make_uint4(A1[0], A1[1], A1[2], A1[3]);

        // RAW: commit writes before frag reads (full compiler barrier too,
        // which pins the uint4-write/bf16x8-read ordering -> no TBAA hole)
        asm volatile("s_waitcnt lgkmcnt(0)" ::: "memory");

        const bf16x8 af0 = *(const bf16x8*)(cb + sp * 36 + q * 4);
        const bf16x8 af1 = *(const bf16x8*)(cb + sp * 36 + 16 + q * 4);

#pragma unroll
        for (int t = 0; t < 4; t++) {
            acc[t] = __builtin_amdgcn_mfma_f32_16x16x32_bf16(af0, wtr[cur][t],     acc[t], 0, 0, 0);
            acc[t] = __builtin_amdgcn_mfma_f32_16x16x32_bf16(af1, wtr[cur][4 + t], acc[t], 0, 0, 0);
        }
    }

    // ---- epilogue: C/D layout col(=o)=lane&15, row(=px)=(lane>>4)*4+r ----
    const int oc = lane & 15;
    const int rg = lane >> 4;
    float* ob = out + (size_t)b * (On * HWn) + pix0 + rg * 4;
#pragma unroll
    for (int t = 0; t < 4; t++) {
        const int o = t * 16 + oc;
        *(f32x4*)(ob + (size_t)o * HWn) = acc[t];
    }
}

// ---------------------------------------------------------------------------
extern "C" void kernel_launch(void* const* d_in, const int* in_sizes, int n_in,
                              void* d_out, int out_size, void* d_ws, size_t ws_size,
                              hipStream_t stream) {
    const float* x      = (const float*)d_in[0];   // (8,64,128,128)
    const float* weight = (const float*)d_in[1];   // (64,64,3,3)
    const float* w_off  = (const float*)d_in[2];   // (18,64)
    const float* b_off  = (const float*)d_in[3];   // (18,)
    float* out = (float*)d_out;                    // (8,64,128,128)

    // workspace: xT 16 MB | wt2 73728 B | woffr 4096 B
    unsigned*       xT    = (unsigned*)d_ws;
    unsigned short* wt2   = (unsigned short*)((char*)d_ws + 16777216);
    unsigned short* woffr = (unsigned short*)((char*)d_ws + 16777216 + 73728);

    prep_kernel<<<2200, 256, 0, stream>>>(x, weight, w_off, xT, wt2, woffr);
    dcn_kernel<<<2048, 256, 0, stream>>>(xT, wt2, woffr, b_off, out);
}

// Round 9
// 130.012 us; speedup vs baseline: 1.3199x; 1.0122x over previous
//
#include <hip/hip_runtime.h>

// Problem constants
#define Bn 8
#define Cn 64
#define Hn 128
#define Wn 128
#define On 64
#define K2n 9
#define HWn (Hn * Wn)          // 16384
#define OLP 20                 // offl row stride (floats): 18 + pad

typedef short bf16x8 __attribute__((ext_vector_type(8)));
typedef float f32x4  __attribute__((ext_vector_type(4)));

__device__ __forceinline__ unsigned f2bf(float f) {
    unsigned u = __float_as_uint(f);
    return (u + 0x7FFFu + ((u >> 16) & 1u)) >> 16;   // RNE fp32->bf16
}
__device__ __forceinline__ unsigned pkbf(float lo, float hi) {
    return f2bf(lo) | (f2bf(hi) << 16);              // verified form (R6)
}
__device__ __forceinline__ float bflo(unsigned u) { return __uint_as_float(u << 16); }
__device__ __forceinline__ float bfhi(unsigned u) { return __uint_as_float(u & 0xFFFF0000u); }

// ---------------------------------------------------------------------------
// prep: blocks [0,2048): transpose x NCHW fp32 -> xT NHWC bf16-pair.
//       blocks [2048,2200): repack weight + w_off into MFMA B-frag order
//       (wt2[slot][lane][8], slot=(k*2+ks)*4+t, o=t*16+(lane&15),
//        c=ks*32+(lane>>4)*8+j; woffr same with slot=ks*2+t, o>=18 -> 0).
// ---------------------------------------------------------------------------
__global__ __launch_bounds__(256) void prep_kernel(
        const float* __restrict__ x,
        const float* __restrict__ w,
        const float* __restrict__ w_off,
        unsigned* __restrict__ xT,
        unsigned short* __restrict__ wt2,
        unsigned short* __restrict__ woffr) {
    const int tid = threadIdx.x;
    const int bid = blockIdx.x;

    if (bid >= 2048) {                           // ---- weight repack ----
        int i = (bid - 2048) * 256 + tid;        // 38912 = 152*256 exactly
        if (i < K2n * On * Cn) {
            int j    = i & 7;
            int lane = (i >> 3) & 63;
            int slot = i >> 9;
            int t  = slot & 3;
            int ks = (slot >> 2) & 1;
            int k  = slot >> 3;
            int o  = t * 16 + (lane & 15);
            int c  = ks * 32 + (lane >> 4) * 8 + j;
            wt2[i] = (unsigned short)f2bf(w[o * (Cn * K2n) + c * K2n + k]);
        } else {
            int idx  = i - K2n * On * Cn;        // < 2048
            int j    = idx & 7;
            int lane = (idx >> 3) & 63;
            int slot = idx >> 9;                 // 0..3 = ks*2 + t
            int t  = slot & 1;
            int ks = slot >> 1;
            int o  = t * 16 + (lane & 15);
            int c  = ks * 32 + (lane >> 4) * 8 + j;
            woffr[idx] = (o < 18) ? (unsigned short)f2bf(w_off[o * Cn + c]) : 0;
        }
        return;
    }

    // ---- transpose: 64px x 64ch tile ----
    __shared__ float tile[64 * 65];
    const int b   = bid >> 8;
    const int px0 = (bid & 255) << 6;

    {   // float4 reads: thread (c, pq) loads px [pq*16, pq*16+16) of channel c
        const int c = tid >> 2, pq = tid & 3;
        const float4* xp4 = (const float4*)(x + (size_t)b * (Cn * HWn)
                                              + (size_t)c * HWn + px0 + pq * 16);
        float4 v[4];
#pragma unroll
        for (int i = 0; i < 4; i++) v[i] = xp4[i];
#pragma unroll
        for (int i = 0; i < 16; i++)
            tile[(pq * 16 + i) * 65 + c] = (&v[0].x)[i];
    }
    __syncthreads();
    {   // pack + coalesced NHWC write
        const int c2 = tid & 31, r = tid >> 5;
        unsigned* dst = xT + ((size_t)b * HWn + px0) * 32;
#pragma unroll
        for (int j = 0; j < 8; j++) {
            const int p = j * 8 + r;
            dst[p * 32 + c2] = pkbf(tile[p * 65 + c2 * 2], tile[p * 65 + c2 * 2 + 1]);
        }
    }
}

// ---------------------------------------------------------------------------
// Main kernel.  Wave owns 16 px.
// Gather lanes are SP-MAJOR: lane = m*4 + c2 (m = pixel, c2 = 16B chunk), so
// each aligned lane-quad reads contiguous 64B -> TA merges into one request.
// Redistribution: R0-VERBATIM double-buffered wave-private chunk LDS tile
// (alternating (k&1) buffers, one lgkm clobber per k), SCALAR combine4.
//
// R9 theory (priced from R8's invariant counters): dcn is L1-return-BW
// bound, not latency/occupancy bound.  Per block per k: gathers 8 KB/wave
// (irreducible, data-dependent) + wt2 B-frags 8 KB/wave -- and ALL 4 WAVES
// LOAD THE SAME wt2 BYTES (bp depends only on lane,k).  ~616 KB/block of
// L1 traffic => ~31 us of pure L1 bandwidth at 64 B/cyc/CU.  Fix: stage
// wt2[k] into LDS once per BLOCK (double-buffered 2x8 KB, one cooperative
// 32 B/thread copy per k), consume via ds_read.  Removes 216 KB/block of
// L1 traffic (-35%).  Cross-wave safety by construction: stage-write(buf,
// k+2) and frag-read(buf, k+1) are separated by the per-k __syncthreads --
// the same cross-barrier discipline as every verified buffer in this
// session (intra-wave fence tricks are abandoned, see R7 ledger).
// Session ledger: f32x2 combine + single-buffer chunk reuse ABANDONED
// (4 corrupt rounds); offl-alias+off[18] hoist verified R7; gather
// ping-pong verified R2/R8; wt register ping-pong (R8) superseded by LDS.
// ---------------------------------------------------------------------------
struct Tap { float w00, w01, w10, w11; int c00, c01, c10, c11; };

__device__ __forceinline__ Tap mktap(int k, float offy, float offx, int h, int w) {
    Tap s;
    const int kh = k / 3, kw = k - kh * 3;
    const float py  = (float)(h - 1 + kh) + offy;
    const float pxf = (float)(w - 1 + kw) + offx;
    const float y0f = floorf(py), x0f = floorf(pxf);
    const float wy1 = py - y0f, wx1 = pxf - x0f;
    const float wy0 = 1.f - wy1, wx0 = 1.f - wx1;
    const int y0 = (int)y0f, x0i = (int)x0f;
    const int y1 = y0 + 1,  x1 = x0i + 1;
    const bool vy0 = (y0 >= 0) && (y0 < Hn);
    const bool vy1 = (y1 >= 0) && (y1 < Hn);
    const bool vx0 = (x0i >= 0) && (x0i < Wn);
    const bool vx1 = (x1 >= 0) && (x1 < Wn);
    const int yc0 = min(max(y0, 0), Hn - 1), yc1 = min(max(y1, 0), Hn - 1);
    const int xc0 = min(max(x0i, 0), Wn - 1), xc1 = min(max(x1, 0), Wn - 1);
    s.w00 = (vy0 && vx0) ? wy0 * wx0 : 0.f;
    s.w01 = (vy0 && vx1) ? wy0 * wx1 : 0.f;
    s.w10 = (vy1 && vx0) ? wy1 * wx0 : 0.f;
    s.w11 = (vy1 && vx1) ? wy1 * wx1 : 0.f;
    s.c00 = (yc0 * Wn + xc0) * 32; s.c01 = (yc0 * Wn + xc1) * 32;
    s.c10 = (yc1 * Wn + xc0) * 32; s.c11 = (yc1 * Wn + xc1) * 32;
    return s;
}

// scalar bilinear combine (R0-verbatim; packed f32x2 variant abandoned)
__device__ __forceinline__ void combine4(unsigned* dst, const uint4* u, const Tap& s) {
#pragma unroll
    for (int i = 0; i < 4; i++) {
        const unsigned a = (&u[0].x)[i], b = (&u[1].x)[i];
        const unsigned c = (&u[2].x)[i], d = (&u[3].x)[i];
        const float slo = s.w00 * bflo(a) + s.w01 * bflo(b)
                        + s.w10 * bflo(c) + s.w11 * bflo(d);
        const float shi = s.w00 * bfhi(a) + s.w01 * bfhi(b)
                        + s.w10 * bfhi(c) + s.w11 * bfhi(d);
        dst[i] = pkbf(slo, shi);
    }
}

__device__ __forceinline__ void gather8(uint4* u, const unsigned* xb,
                                        const Tap& s, int c2) {
    const unsigned* g00 = xb + s.c00 + c2 * 4;
    const unsigned* g01 = xb + s.c01 + c2 * 4;
    const unsigned* g10 = xb + s.c10 + c2 * 4;
    const unsigned* g11 = xb + s.c11 + c2 * 4;
    u[0] = *(const uint4*)g00;          // half 0: chunk c2   (ks=0)
    u[1] = *(const uint4*)g01;
    u[2] = *(const uint4*)g10;
    u[3] = *(const uint4*)g11;
    u[4] = *(const uint4*)(g00 + 16);   // half 1: chunk 4+c2 (ks=1)
    u[5] = *(const uint4*)(g01 + 16);
    u[6] = *(const uint4*)(g10 + 16);
    u[7] = *(const uint4*)(g11 + 16);
}

__global__ __launch_bounds__(256, 2) void dcn_kernel(
        const unsigned* __restrict__ xT,
        const unsigned short* __restrict__ wt2,
        const unsigned short* __restrict__ woffr,
        const float* __restrict__ b_off,
        float* __restrict__ out) {
    // chunk tiles (first 5120 B double as offl during the prologue, R7-
    // verified) + double-buffered wt2 B-matrix stage (2 x 8192 B)
    __shared__ __align__(16) unsigned shmem[4][2][16 * 36];    // 18432 B
    __shared__ __align__(16) unsigned short wtl[2][8 * 512];   // 16384 B
    float* const offl = (float*)&shmem[0][0][0];               // prologue alias

    const int tid = threadIdx.x;
    const int bid = blockIdx.x;
    // XCD swizzle: bid&7 = image -> per-XCD L2 holds one 2.1MB bf16 image
    const int logical = ((bid & 7) << 8) | (bid >> 3);         // 2048 blocks
    const int b   = logical >> 8;
    const int hw0 = (logical & 255) << 6;

    const int lane = tid & 63;
    const int wv   = tid >> 6;
    const int q    = lane >> 4;        // consumer: chunk index / K-half group
    const int sp   = lane & 15;        // consumer + prologue pixel
    const int m    = lane >> 2;        // producer pixel (sp-major gather)
    const int c2   = lane & 3;         // producer 16B-chunk within 64B half
    const int pix0 = hw0 + wv * 16;
    const int pix  = pix0 + sp;

    const unsigned* xb = xT + (size_t)b * (HWn * 32);          // uint = 2 channels

    // ---- offset conv via MFMA (R6-verified) ------------------------------
    {
        union { uint4 u; bf16x8 v; } aw0, aw1;
        aw0.u = *(const uint4*)(xb + pix * 32 + q * 4);
        aw1.u = *(const uint4*)(xb + pix * 32 + 16 + q * 4);
        f32x4 oa0 = (f32x4){0.f, 0.f, 0.f, 0.f};
        f32x4 oa1 = (f32x4){0.f, 0.f, 0.f, 0.f};
        const bf16x8 bo00 = *(const bf16x8*)(woffr + 0 * 512 + lane * 8);
        const bf16x8 bo01 = *(const bf16x8*)(woffr + 1 * 512 + lane * 8);
        const bf16x8 bo10 = *(const bf16x8*)(woffr + 2 * 512 + lane * 8);
        const bf16x8 bo11 = *(const bf16x8*)(woffr + 3 * 512 + lane * 8);
        oa0 = __builtin_amdgcn_mfma_f32_16x16x32_bf16(aw0.v, bo00, oa0, 0, 0, 0);
        oa1 = __builtin_amdgcn_mfma_f32_16x16x32_bf16(aw0.v, bo01, oa1, 0, 0, 0);
        oa0 = __builtin_amdgcn_mfma_f32_16x16x32_bf16(aw1.v, bo10, oa0, 0, 0, 0);
        oa1 = __builtin_amdgcn_mfma_f32_16x16x32_bf16(aw1.v, bo11, oa1, 0, 0, 0);
        const int oc = lane & 15, rg = lane >> 4;
        float* ol = offl + wv * (16 * OLP);
        const float bo_a = b_off[oc];
#pragma unroll
        for (int r = 0; r < 4; r++)
            ol[(rg * 4 + r) * OLP + oc] = oa0[r] + bo_a;
        if (oc < 2) {
            const float bo_b = b_off[16 + oc];
#pragma unroll
            for (int r = 0; r < 4; r++)
                ol[(rg * 4 + r) * OLP + 16 + oc] = oa1[r] + bo_b;
        }
    }
    // stage wt2[k=0] into wtl[0] (separate LDS region from offl: no overlap
    // with offset staging; published by the __syncthreads below)
    {
        const uint4* s0 = (const uint4*)(wt2) + tid * 2;
        uint4* d0 = (uint4*)(&wtl[0][0]) + tid * 2;
        d0[0] = s0[0]; d0[1] = s0[1];
    }
    asm volatile("s_waitcnt lgkmcnt(0)" ::: "memory");   // per-wave LDS hand-off

    // hoist this lane's 18 offsets (pixel m) into registers (R2/R7-verified),
    // making the offl region dead before any chunk write
    const float* olp = offl + wv * (16 * OLP) + m * OLP;
    float off[18];
#pragma unroll
    for (int i = 0; i < 9; i++) {
        const float2 o2 = *(const float2*)(olp + 2 * i);
        off[2 * i]     = o2.x;
        off[2 * i + 1] = o2.y;
    }

    // cross-wave barrier: all offl reads done before chunk writes; wtl[0]
    // staging visible to all waves
    __syncthreads();

    // producer-side state: this lane samples pixel m
    const int pixm = pix0 + m;
    const int hm = pixm >> 7;
    const int wm = pixm & 127;
    unsigned* cwv = &shmem[wv][0][0];                    // 2 x 576 dwords

    f32x4 acc[4];
#pragma unroll
    for (int t = 0; t < 4; t++) acc[t] = (f32x4){0.f, 0.f, 0.f, 0.f};

    // ---- software pipeline state: gather regs for k=0 (R2/R8-verified) ---
    uint4 u[2][8];                     // ping-pong gather state
    Tap   tp[2];
    tp[0] = mktap(0, off[0], off[1], hm, wm);
    gather8(u[0], xb, tp[0], c2);

#pragma unroll
    for (int k = 0; k < K2n; k++) {
        const int cur = k & 1, nxt = cur ^ 1;

        // ---- stage wt2[k+1] -> wtl[nxt] (cooperative, 32 B/thread) and
        //      issue k+1's gathers; both before this iteration's clobber so
        //      their latency hides under combine(k) + MFMA(k) ----
        if (k + 1 < K2n) {
            const uint4* sn = (const uint4*)(wt2 + (size_t)(k + 1) * 4096) + tid * 2;
            uint4* dn = (uint4*)(&wtl[nxt][0]) + tid * 2;
            dn[0] = sn[0]; dn[1] = sn[1];
            tp[nxt] = mktap(k + 1, off[2 * k + 2], off[2 * k + 3], hm, wm);
            gather8(u[nxt], xb, tp[nxt], c2);
        }

        // ---- combine current k's taps + pack ----
        unsigned A0[4], A1[4];
        combine4(A0, &u[cur][0], tp[cur]);  // channels c2*8..+8      (ks=0)
        combine4(A1, &u[cur][4], tp[cur]);  // channels 32+c2*8..+8   (ks=1)

        // ---- redistribute via double-buffered wave-private chunk LDS ----
        unsigned* cb = cwv + cur * 576;
        *(uint4*)(cb + m * 36 + c2 * 4)      = make_uint4(A0[0], A0[1], A0[2], A0[3]);
        *(uint4*)(cb + m * 36 + 16 + c2 * 4) = make_uint4(A1[0], A1[1], A1[2], A1[3]);

        // RAW: commit writes before frag reads (full compiler barrier too,
        // which pins the uint4-write/bf16x8-read ordering -> no TBAA hole)
        asm volatile("s_waitcnt lgkmcnt(0)" ::: "memory");

        const bf16x8 af0 = *(const bf16x8*)(cb + sp * 36 + q * 4);
        const bf16x8 af1 = *(const bf16x8*)(cb + sp * 36 + 16 + q * 4);

        // B-frags from the block-shared LDS stage (was 8 KB/wave/k from L1)
        const unsigned short* bl = &wtl[cur][lane * 8];
#pragma unroll
        for (int t = 0; t < 4; t++) {
            const bf16x8 b0 = *(const bf16x8*)(bl + t * 512);
            acc[t] = __builtin_amdgcn_mfma_f32_16x16x32_bf16(af0, b0, acc[t], 0, 0, 0);
            const bf16x8 b1 = *(const bf16x8*)(bl + (4 + t) * 512);
            acc[t] = __builtin_amdgcn_mfma_f32_16x16x32_bf16(af1, b1, acc[t], 0, 0, 0);
        }

        // publish wtl[nxt] staging + protect wtl[cur] from k+1's re-stage:
        // all waves' frag reads of wtl[cur] complete before iteration k+1
        // overwrites it (cross-barrier discipline, no hand-rolled fences)
        __syncthreads();
    }

    // ---- epilogue: C/D layout col(=o)=lane&15, row(=px)=(lane>>4)*4+r ----
    const int oc = lane & 15;
    const int rg = lane >> 4;
    float* ob = out + (size_t)b * (On * HWn) + pix0 + rg * 4;
#pragma unroll
    for (int t = 0; t < 4; t++) {
        const int o = t * 16 + oc;
        *(f32x4*)(ob + (size_t)o * HWn) = acc[t];
    }
}

// ---------------------------------------------------------------------------
extern "C" void kernel_launch(void* const* d_in, const int* in_sizes, int n_in,
                              void* d_out, int out_size, void* d_ws, size_t ws_size,
                              hipStream_t stream) {
    const float* x      = (const float*)d_in[0];   // (8,64,128,128)
    const float* weight = (const float*)d_in[1];   // (64,64,3,3)
    const float* w_off  = (const float*)d_in[2];   // (18,64)
    const float* b_off  = (const float*)d_in[3];   // (18,)
    float* out = (float*)d_out;                    // (8,64,128,128)

    // workspace: xT 16 MB | wt2 73728 B | woffr 4096 B
    unsigned*       xT    = (unsigned*)d_ws;
    unsigned short* wt2   = (unsigned short*)((char*)d_ws + 16777216);
    unsigned short* woffr = (unsigned short*)((char*)d_ws + 16777216 + 73728);

    prep_kernel<<<2200, 256, 0, stream>>>(x, weight, w_off, xT, wt2, woffr);
    dcn_kernel<<<2048, 256, 0, stream>>>(xT, wt2, woffr, b_off, out);
}

// Round 10
// 124.070 us; speedup vs baseline: 1.3831x; 1.0479x over previous
//
#include <hip/hip_runtime.h>

// Problem constants
#define Bn 8
#define Cn 64
#define Hn 128
#define Wn 128
#define On 64
#define K2n 9
#define HWn (Hn * Wn)          // 16384
#define OLP 20                 // offl row stride (floats): 18 + pad

typedef short bf16x8 __attribute__((ext_vector_type(8)));
typedef float f32x4  __attribute__((ext_vector_type(4)));

__device__ __forceinline__ unsigned f2bf(float f) {
    unsigned u = __float_as_uint(f);
    return (u + 0x7FFFu + ((u >> 16) & 1u)) >> 16;   // RNE fp32->bf16
}
__device__ __forceinline__ unsigned pkbf(float lo, float hi) {
    return f2bf(lo) | (f2bf(hi) << 16);              // verified form (R6)
}
__device__ __forceinline__ float bflo(unsigned u) { return __uint_as_float(u << 16); }
__device__ __forceinline__ float bfhi(unsigned u) { return __uint_as_float(u & 0xFFFF0000u); }

// R10: 3-op bf16 pair pack for the inner loop: round-half-up (+0x8000) per
// half, then ONE v_perm_b32 assembles [hi.b3,hi.b2,lo.b3,lo.b2].  Replaces
// the 7-op RNE merge.  Differs from RNE only on exact-tie mantissas
// (prob ~2^-16/value, +-1 ulp) -- absmax headroom is 2.4x.
__device__ __forceinline__ unsigned pkbf2(float lo, float hi) {
    const unsigned rlo = __float_as_uint(lo) + 0x8000u;
    const unsigned rhi = __float_as_uint(hi) + 0x8000u;
    return __builtin_amdgcn_perm(rhi, rlo, 0x07060302u);
}

// ---------------------------------------------------------------------------
// prep: blocks [0,2048): transpose x NCHW fp32 -> xT NHWC bf16-pair.
//       blocks [2048,2200): repack weight + w_off into MFMA B-frag order
//       (wt2[slot][lane][8], slot=(k*2+ks)*4+t, o=t*16+(lane&15),
//        c=ks*32+(lane>>4)*8+j; woffr same with slot=ks*2+t, o>=18 -> 0).
//       prep keeps the exact RNE pack (unchanged, verified).
// ---------------------------------------------------------------------------
__global__ __launch_bounds__(256) void prep_kernel(
        const float* __restrict__ x,
        const float* __restrict__ w,
        const float* __restrict__ w_off,
        unsigned* __restrict__ xT,
        unsigned short* __restrict__ wt2,
        unsigned short* __restrict__ woffr) {
    const int tid = threadIdx.x;
    const int bid = blockIdx.x;

    if (bid >= 2048) {                           // ---- weight repack ----
        int i = (bid - 2048) * 256 + tid;        // 38912 = 152*256 exactly
        if (i < K2n * On * Cn) {
            int j    = i & 7;
            int lane = (i >> 3) & 63;
            int slot = i >> 9;
            int t  = slot & 3;
            int ks = (slot >> 2) & 1;
            int k  = slot >> 3;
            int o  = t * 16 + (lane & 15);
            int c  = ks * 32 + (lane >> 4) * 8 + j;
            wt2[i] = (unsigned short)f2bf(w[o * (Cn * K2n) + c * K2n + k]);
        } else {
            int idx  = i - K2n * On * Cn;        // < 2048
            int j    = idx & 7;
            int lane = (idx >> 3) & 63;
            int slot = idx >> 9;                 // 0..3 = ks*2 + t
            int t  = slot & 1;
            int ks = slot >> 1;
            int o  = t * 16 + (lane & 15);
            int c  = ks * 32 + (lane >> 4) * 8 + j;
            woffr[idx] = (o < 18) ? (unsigned short)f2bf(w_off[o * Cn + c]) : 0;
        }
        return;
    }

    // ---- transpose: 64px x 64ch tile ----
    __shared__ float tile[64 * 65];
    const int b   = bid >> 8;
    const int px0 = (bid & 255) << 6;

    {   // float4 reads: thread (c, pq) loads px [pq*16, pq*16+16) of channel c
        const int c = tid >> 2, pq = tid & 3;
        const float4* xp4 = (const float4*)(x + (size_t)b * (Cn * HWn)
                                              + (size_t)c * HWn + px0 + pq * 16);
        float4 v[4];
#pragma unroll
        for (int i = 0; i < 4; i++) v[i] = xp4[i];
#pragma unroll
        for (int i = 0; i < 16; i++)
            tile[(pq * 16 + i) * 65 + c] = (&v[0].x)[i];
    }
    __syncthreads();
    {   // pack + coalesced NHWC write
        const int c2 = tid & 31, r = tid >> 5;
        unsigned* dst = xT + ((size_t)b * HWn + px0) * 32;
#pragma unroll
        for (int j = 0; j < 8; j++) {
            const int p = j * 8 + r;
            dst[p * 32 + c2] = pkbf(tile[p * 65 + c2 * 2], tile[p * 65 + c2 * 2 + 1]);
        }
    }
}

// ---------------------------------------------------------------------------
// Main kernel.  Wave owns 16 px.
// Gather lanes are SP-MAJOR: lane = m*4 + c2; each aligned lane-quad reads
// contiguous 64B -> TA merges into one request.  Redistribution: R0-verbatim
// double-buffered wave-private chunk LDS tile (alternating (k&1) buffers,
// one lgkm clobber per k), SCALAR combine FMAs.  wt2 staged in LDS per
// block (R9-verified, double-buffered, cross-barrier discipline).
//
// R10 (VALU diet, data path untouched):
//  - combine pack: pkbf2 (2 adds + v_perm) instead of 7-op RNE merge;
//  - mktap: unsigned-range validity (1 cmp/coord) + zeroed 1-D weights;
//  - staging copy at 16B lane stride (tid, tid+256): R9's tid*32B pattern
//    touched half the banks per b128 phase (bank-conflict 1.77M->2.95M).
// Session ledger: f32x2 packed combine + single-buffer chunk reuse
// ABANDONED (4 corrupt rounds); ds_bpermute operates within 32-lane halves
// (R1's actual bug -- cross-half mapping); offl-alias+off[18] hoist
// verified R7; gather ping-pong verified R2/R8; wt2 LDS stage verified R9.
// ---------------------------------------------------------------------------
struct Tap { float w00, w01, w10, w11; int c00, c01, c10, c11; };

__device__ __forceinline__ Tap mktap(int k, float offy, float offx, int h, int w) {
    Tap s;
    const int kh = k / 3, kw = k - kh * 3;
    const float py  = (float)(h - 1 + kh) + offy;
    const float pxf = (float)(w - 1 + kw) + offx;
    const float y0f = floorf(py), x0f = floorf(pxf);
    const float wy1 = py - y0f, wx1 = pxf - x0f;
    const float wy0 = 1.f - wy1, wx0 = 1.f - wx1;
    const int y0 = (int)y0f, x0i = (int)x0f;
    const int y1 = y0 + 1,  x1 = x0i + 1;
    // unsigned-range validity: 1 cmp per coord (y<0 wraps to huge unsigned);
    // zero the 1-D weights, then form the 4 products (exact: 0*w == 0, all
    // weights finite & >= 0)
    const float zy0 = ((unsigned)y0  < (unsigned)Hn) ? wy0 : 0.f;
    const float zy1 = ((unsigned)y1  < (unsigned)Hn) ? wy1 : 0.f;
    const float zx0 = ((unsigned)x0i < (unsigned)Wn) ? wx0 : 0.f;
    const float zx1 = ((unsigned)x1  < (unsigned)Wn) ? wx1 : 0.f;
    s.w00 = zy0 * zx0; s.w01 = zy0 * zx1;
    s.w10 = zy1 * zx0; s.w11 = zy1 * zx1;
    const int yc0 = min(max(y0, 0), Hn - 1), yc1 = min(max(y1, 0), Hn - 1);
    const int xc0 = min(max(x0i, 0), Wn - 1), xc1 = min(max(x1, 0), Wn - 1);
    s.c00 = (yc0 * Wn + xc0) * 32; s.c01 = (yc0 * Wn + xc1) * 32;
    s.c10 = (yc1 * Wn + xc0) * 32; s.c11 = (yc1 * Wn + xc1) * 32;
    return s;
}

// scalar bilinear combine FMAs (R0-verbatim) + 3-op perm pack (R10)
__device__ __forceinline__ void combine4(unsigned* dst, const uint4* u, const Tap& s) {
#pragma unroll
    for (int i = 0; i < 4; i++) {
        const unsigned a = (&u[0].x)[i], b = (&u[1].x)[i];
        const unsigned c = (&u[2].x)[i], d = (&u[3].x)[i];
        const float slo = s.w00 * bflo(a) + s.w01 * bflo(b)
                        + s.w10 * bflo(c) + s.w11 * bflo(d);
        const float shi = s.w00 * bfhi(a) + s.w01 * bfhi(b)
                        + s.w10 * bfhi(c) + s.w11 * bfhi(d);
        dst[i] = pkbf2(slo, shi);
    }
}

__device__ __forceinline__ void gather8(uint4* u, const unsigned* xb,
                                        const Tap& s, int c2) {
    const unsigned* g00 = xb + s.c00 + c2 * 4;
    const unsigned* g01 = xb + s.c01 + c2 * 4;
    const unsigned* g10 = xb + s.c10 + c2 * 4;
    const unsigned* g11 = xb + s.c11 + c2 * 4;
    u[0] = *(const uint4*)g00;          // half 0: chunk c2   (ks=0)
    u[1] = *(const uint4*)g01;
    u[2] = *(const uint4*)g10;
    u[3] = *(const uint4*)g11;
    u[4] = *(const uint4*)(g00 + 16);   // half 1: chunk 4+c2 (ks=1)
    u[5] = *(const uint4*)(g01 + 16);
    u[6] = *(const uint4*)(g10 + 16);
    u[7] = *(const uint4*)(g11 + 16);
}

__global__ __launch_bounds__(256, 2) void dcn_kernel(
        const unsigned* __restrict__ xT,
        const unsigned short* __restrict__ wt2,
        const unsigned short* __restrict__ woffr,
        const float* __restrict__ b_off,
        float* __restrict__ out) {
    // chunk tiles (first 5120 B double as offl during the prologue, R7-
    // verified) + double-buffered wt2 B-matrix stage (2 x 8192 B)
    __shared__ __align__(16) unsigned shmem[4][2][16 * 36];    // 18432 B
    __shared__ __align__(16) unsigned short wtl[2][8 * 512];   // 16384 B
    float* const offl = (float*)&shmem[0][0][0];               // prologue alias

    const int tid = threadIdx.x;
    const int bid = blockIdx.x;
    // XCD swizzle: bid&7 = image -> per-XCD L2 holds one 2.1MB bf16 image
    const int logical = ((bid & 7) << 8) | (bid >> 3);         // 2048 blocks
    const int b   = logical >> 8;
    const int hw0 = (logical & 255) << 6;

    const int lane = tid & 63;
    const int wv   = tid >> 6;
    const int q    = lane >> 4;        // consumer: chunk index / K-half group
    const int sp   = lane & 15;        // consumer + prologue pixel
    const int m    = lane >> 2;        // producer pixel (sp-major gather)
    const int c2   = lane & 3;         // producer 16B-chunk within 64B half
    const int pix0 = hw0 + wv * 16;
    const int pix  = pix0 + sp;

    const unsigned* xb = xT + (size_t)b * (HWn * 32);          // uint = 2 channels

    // ---- offset conv via MFMA (R6-verified) ------------------------------
    {
        union { uint4 u; bf16x8 v; } aw0, aw1;
        aw0.u = *(const uint4*)(xb + pix * 32 + q * 4);
        aw1.u = *(const uint4*)(xb + pix * 32 + 16 + q * 4);
        f32x4 oa0 = (f32x4){0.f, 0.f, 0.f, 0.f};
        f32x4 oa1 = (f32x4){0.f, 0.f, 0.f, 0.f};
        const bf16x8 bo00 = *(const bf16x8*)(woffr + 0 * 512 + lane * 8);
        const bf16x8 bo01 = *(const bf16x8*)(woffr + 1 * 512 + lane * 8);
        const bf16x8 bo10 = *(const bf16x8*)(woffr + 2 * 512 + lane * 8);
        const bf16x8 bo11 = *(const bf16x8*)(woffr + 3 * 512 + lane * 8);
        oa0 = __builtin_amdgcn_mfma_f32_16x16x32_bf16(aw0.v, bo00, oa0, 0, 0, 0);
        oa1 = __builtin_amdgcn_mfma_f32_16x16x32_bf16(aw0.v, bo01, oa1, 0, 0, 0);
        oa0 = __builtin_amdgcn_mfma_f32_16x16x32_bf16(aw1.v, bo10, oa0, 0, 0, 0);
        oa1 = __builtin_amdgcn_mfma_f32_16x16x32_bf16(aw1.v, bo11, oa1, 0, 0, 0);
        const int oc = lane & 15, rg = lane >> 4;
        float* ol = offl + wv * (16 * OLP);
        const float bo_a = b_off[oc];
#pragma unroll
        for (int r = 0; r < 4; r++)
            ol[(rg * 4 + r) * OLP + oc] = oa0[r] + bo_a;
        if (oc < 2) {
            const float bo_b = b_off[16 + oc];
#pragma unroll
            for (int r = 0; r < 4; r++)
                ol[(rg * 4 + r) * OLP + 16 + oc] = oa1[r] + bo_b;
        }
    }
    // stage wt2[k=0] into wtl[0] at 16B lane stride (conflict-floor b128
    // pattern; R9's tid*32B stride was 2x the floor)
    {
        const uint4* s0 = (const uint4*)(wt2);
        uint4* d0 = (uint4*)(&wtl[0][0]);
        d0[tid]       = s0[tid];
        d0[tid + 256] = s0[tid + 256];
    }
    asm volatile("s_waitcnt lgkmcnt(0)" ::: "memory");   // per-wave LDS hand-off

    // hoist this lane's 18 offsets (pixel m) into registers (R2/R7-verified),
    // making the offl region dead before any chunk write
    const float* olp = offl + wv * (16 * OLP) + m * OLP;
    float off[18];
#pragma unroll
    for (int i = 0; i < 9; i++) {
        const float2 o2 = *(const float2*)(olp + 2 * i);
        off[2 * i]     = o2.x;
        off[2 * i + 1] = o2.y;
    }

    // cross-wave barrier: all offl reads done before chunk writes; wtl[0]
    // staging visible to all waves
    __syncthreads();

    // producer-side state: this lane samples pixel m
    const int pixm = pix0 + m;
    const int hm = pixm >> 7;
    const int wm = pixm & 127;
    unsigned* cwv = &shmem[wv][0][0];                    // 2 x 576 dwords

    f32x4 acc[4];
#pragma unroll
    for (int t = 0; t < 4; t++) acc[t] = (f32x4){0.f, 0.f, 0.f, 0.f};

    // ---- software pipeline state: gather regs for k=0 (R2/R8-verified) ---
    uint4 u[2][8];                     // ping-pong gather state
    Tap   tp[2];
    tp[0] = mktap(0, off[0], off[1], hm, wm);
    gather8(u[0], xb, tp[0], c2);

#pragma unroll
    for (int k = 0; k < K2n; k++) {
        const int cur = k & 1, nxt = cur ^ 1;

        // ---- stage wt2[k+1] -> wtl[nxt] (16B lane stride) and issue k+1's
        //      gathers; both before this iteration's clobber so their
        //      latency hides under combine(k) + MFMA(k) ----
        if (k + 1 < K2n) {
            const uint4* sn = (const uint4*)(wt2 + (size_t)(k + 1) * 4096);
            uint4* dn = (uint4*)(&wtl[nxt][0]);
            dn[tid]       = sn[tid];
            dn[tid + 256] = sn[tid + 256];
            tp[nxt] = mktap(k + 1, off[2 * k + 2], off[2 * k + 3], hm, wm);
            gather8(u[nxt], xb, tp[nxt], c2);
        }

        // ---- combine current k's taps + pack ----
        unsigned A0[4], A1[4];
        combine4(A0, &u[cur][0], tp[cur]);  // channels c2*8..+8      (ks=0)
        combine4(A1, &u[cur][4], tp[cur]);  // channels 32+c2*8..+8   (ks=1)

        // ---- redistribute via double-buffered wave-private chunk LDS ----
        unsigned* cb = cwv + cur * 576;
        *(uint4*)(cb + m * 36 + c2 * 4)      = make_uint4(A0[0], A0[1], A0[2], A0[3]);
        *(uint4*)(cb + m * 36 + 16 + c2 * 4) = make_uint4(A1[0], A1[1], A1[2], A1[3]);

        // RAW: commit writes before frag reads (full compiler barrier too,
        // which pins the uint4-write/bf16x8-read ordering -> no TBAA hole)
        asm volatile("s_waitcnt lgkmcnt(0)" ::: "memory");

        const bf16x8 af0 = *(const bf16x8*)(cb + sp * 36 + q * 4);
        const bf16x8 af1 = *(const bf16x8*)(cb + sp * 36 + 16 + q * 4);

        // B-frags from the block-shared LDS stage (R9-verified)
        const unsigned short* bl = &wtl[cur][lane * 8];
#pragma unroll
        for (int t = 0; t < 4; t++) {
            const bf16x8 b0 = *(const bf16x8*)(bl + t * 512);
            acc[t] = __builtin_amdgcn_mfma_f32_16x16x32_bf16(af0, b0, acc[t], 0, 0, 0);
            const bf16x8 b1 = *(const bf16x8*)(bl + (4 + t) * 512);
            acc[t] = __builtin_amdgcn_mfma_f32_16x16x32_bf16(af1, b1, acc[t], 0, 0, 0);
        }

        // publish wtl[nxt] staging + protect wtl[cur] from k+1's re-stage
        // (cross-barrier discipline, no hand-rolled fences)
        __syncthreads();
    }

    // ---- epilogue: C/D layout col(=o)=lane&15, row(=px)=(lane>>4)*4+r ----
    const int oc = lane & 15;
    const int rg = lane >> 4;
    float* ob = out + (size_t)b * (On * HWn) + pix0 + rg * 4;
#pragma unroll
    for (int t = 0; t < 4; t++) {
        const int o = t * 16 + oc;
        *(f32x4*)(ob + (size_t)o * HWn) = acc[t];
    }
}

// ---------------------------------------------------------------------------
extern "C" void kernel_launch(void* const* d_in, const int* in_sizes, int n_in,
                              void* d_out, int out_size, void* d_ws, size_t ws_size,
                              hipStream_t stream) {
    const float* x      = (const float*)d_in[0];   // (8,64,128,128)
    const float* weight = (const float*)d_in[1];   // (64,64,3,3)
    const float* w_off  = (const float*)d_in[2];   // (18,64)
    const float* b_off  = (const float*)d_in[3];   // (18,)
    float* out = (float*)d_out;                    // (8,64,128,128)

    // workspace: xT 16 MB | wt2 73728 B | woffr 4096 B
    unsigned*       xT    = (unsigned*)d_ws;
    unsigned short* wt2   = (unsigned short*)((char*)d_ws + 16777216);
    unsigned short* woffr = (unsigned short*)((char*)d_ws + 16777216 + 73728);

    prep_kernel<<<2200, 256, 0, stream>>>(x, weight, w_off, xT, wt2, woffr);
    dcn_kernel<<<2048, 256, 0, stream>>>(xT, wt2, woffr, b_off, out);
}